// Round 5
// baseline (116.798 us; speedup 1.0000x reference)
//
#include <hip/hip_runtime.h>
#include <math.h>

// Circle GIoU loss, summed over N pairs.
// x, y: (N,3) float32 row-major [cx, cy, r]. Output: scalar float32 sum.
//
// R5: AoS (12B circles) makes direct per-circle float4 loads 48B-lane-strided
// (3KB footprint/instr). Fix: unit-stride global float4 loads -> LDS staging
// -> per-circle LDS reads. 1024 blocks x 256 thr, 4 batches of 1024 circles
// per block, global prefetch of batch i+1 overlaps compute of batch i.
// NOTE: total dur_us carries ~90 us of fixed harness reset cost
// (268 MB d_ws poison + input restores) — controllable part is stage1+2.

#define EPSF   1e-07f
#define ACLIPF (1.0f - 1e-06f)
#define PIF    3.14159265358979323846f

__device__ __forceinline__ float frcp(float x)  { return __builtin_amdgcn_rcpf(x); }
__device__ __forceinline__ float fsqrt(float x) { return __builtin_amdgcn_sqrtf(x); }

// Abramowitz & Stegun 4.4.45: acos(x) ~ sqrt(1-x)*poly(x); abs err < 6.7e-5
__device__ __forceinline__ float fast_acos(float x) {
    float ax = fabsf(x);
    float p = fmaf(fmaf(fmaf(-0.0187293f, ax, 0.0742610f), ax, -0.2121144f), ax, 1.5707288f);
    float r = fsqrt(1.0f - ax) * p;
    return x < 0.0f ? PIF - r : r;
}

__device__ __forceinline__ float circle_giou(float cx0, float cy0, float r0,
                                             float cx1, float cy1, float r1) {
    float dx = cx0 - cx1, dy = cy0 - cy1;
    float d2 = fmaf(dx, dx, dy * dy);
    float d  = fsqrt(fmaxf(d2, EPSF));
    float rmax = fmaxf(r0, r1), rmin = fminf(r0, r1);
    float rdiff = rmax - rmin, rsum = r0 + r1;
    bool lens      = (d < rsum) && (d > rdiff);
    bool contained = (d <= rdiff);

    float r0s = r0 * r0, r1s = r1 * r1;
    float inv0 = frcp(fmaxf(2.0f * d * r0, EPSF));
    float inv1 = frcp(fmaxf(2.0f * d * r1, EPSF));
    float cos0 = fminf(fmaxf((d2 + r0s - r1s) * inv0, -ACLIPF), ACLIPF);
    float cos1 = fminf(fmaxf((d2 + r1s - r0s) * inv1, -ACLIPF), ACLIPF);

    float t = (rsum * rsum - d2) * (d2 - rdiff * rdiff);
    float t_safe = lens ? fmaxf(t, EPSF) : 1.0f;
    float lens_area = r0s * fast_acos(cos0) + r1s * fast_acos(cos1) - 0.5f * fsqrt(t_safe);
    float inter = lens ? lens_area : (contained ? PIF * rmin * rmin : 0.0f);
    float uni = PIF * (r0s + r1s) - inter;
    float iou = inter * frcp(fmaxf(uni, EPSF));

    float alpha = fast_acos(fminf(rdiff * frcp(d), ACLIPF));
    float h2 = d2 - rdiff * rdiff;
    float h2_safe = contained ? 1.0f : fmaxf(h2, EPSF);
    float hull_open = rmax * rmax * (PIF - alpha) + rmin * rmin * alpha
                      + (rmax + rmin) * fsqrt(h2_safe);
    float hull = contained ? PIF * rmax * rmax : hull_open;

    return 1.0f - (iou - (hull - uni) * frcp(fmaxf(hull, EPSF)));
}

__device__ __forceinline__ float giou4(float4 xa, float4 xb, float4 xc,
                                       float4 ya, float4 yb, float4 yc) {
    float s = 0.0f;
    s += circle_giou(xa.x, xa.y, xa.z,  ya.x, ya.y, ya.z);
    s += circle_giou(xa.w, xb.x, xb.y,  ya.w, yb.x, yb.y);
    s += circle_giou(xb.z, xb.w, xc.x,  yb.z, yb.w, yc.x);
    s += circle_giou(xc.y, xc.z, xc.w,  yc.y, yc.z, yc.w);
    return s;
}

#define NBATCH 4   // 4 batches of 1024 circles per block

__global__ __launch_bounds__(256)
void GIOULOSS_19524921327670_stage1(const float4* __restrict__ x4,
                                    const float4* __restrict__ y4,
                                    float* __restrict__ partial) {
    // Per batch: block covers 1024 circles = 768 float4 per input.
    __shared__ float4 bufx[768];
    __shared__ float4 bufy[768];

    const int t = threadIdx.x;
    const int b = blockIdx.x;

    // Prefetch batch 0 (unit-stride across lanes: 1KB per wave-instr).
    int base = (b * NBATCH + 0) * 768;
    float4 gx0 = x4[base + t], gx1 = x4[base + 256 + t], gx2 = x4[base + 512 + t];
    float4 gy0 = y4[base + t], gy1 = y4[base + 256 + t], gy2 = y4[base + 512 + t];

    float acc = 0.0f;
    #pragma unroll
    for (int i = 0; i < NBATCH; ++i) {
        __syncthreads();                 // protect previous batch's LDS reads
        bufx[t] = gx0; bufx[256 + t] = gx1; bufx[512 + t] = gx2;
        bufy[t] = gy0; bufy[256 + t] = gy1; bufy[512 + t] = gy2;

        if (i + 1 < NBATCH) {            // prefetch next batch during compute
            int nb = (b * NBATCH + i + 1) * 768;
            gx0 = x4[nb + t]; gx1 = x4[nb + 256 + t]; gx2 = x4[nb + 512 + t];
            gy0 = y4[nb + t]; gy1 = y4[nb + 256 + t]; gy2 = y4[nb + 512 + t];
        }
        __syncthreads();

        // Per-circle read-back: thread t -> circles [4t, 4t+4) of this batch,
        // i.e. floats [12t, 12t+12) = three 16B-aligned float4s at 48B stride.
        const float4* px = (const float4*)((const float*)bufx + 12 * t);
        const float4* py = (const float4*)((const float*)bufy + 12 * t);
        float4 xa = px[0], xb = px[1], xc = px[2];
        float4 ya = py[0], yb = py[1], yc = py[2];
        acc += giou4(xa, xb, xc, ya, yb, yc);
    }

    #pragma unroll
    for (int off = 32; off > 0; off >>= 1)
        acc += __shfl_down(acc, off, 64);

    __shared__ float wave_sums[4];
    int lane = threadIdx.x & 63;
    int wave = threadIdx.x >> 6;
    if (lane == 0) wave_sums[wave] = acc;
    __syncthreads();
    if (threadIdx.x == 0)
        partial[blockIdx.x] = wave_sums[0] + wave_sums[1] + wave_sums[2] + wave_sums[3];
}

// Sums 1024 block partials with one 256-thread block.
__global__ __launch_bounds__(256)
void GIOULOSS_19524921327670_stage2(const float* __restrict__ partial,
                                    float* __restrict__ out) {
    const float4* p4 = (const float4*)partial;   // 1024 floats = 256 float4
    float4 a = p4[threadIdx.x];
    float acc = (a.x + a.y) + (a.z + a.w);

    #pragma unroll
    for (int off = 32; off > 0; off >>= 1)
        acc += __shfl_down(acc, off, 64);

    __shared__ float wave_sums[4];
    int lane = threadIdx.x & 63;
    int wave = threadIdx.x >> 6;
    if (lane == 0) wave_sums[wave] = acc;
    __syncthreads();
    if (threadIdx.x == 0)
        out[0] = wave_sums[0] + wave_sums[1] + wave_sums[2] + wave_sums[3];
}

extern "C" void kernel_launch(void* const* d_in, const int* in_sizes, int n_in,
                              void* d_out, int out_size, void* d_ws, size_t ws_size,
                              hipStream_t stream) {
    const float4* x4 = (const float4*)d_in[0];
    const float4* y4 = (const float4*)d_in[1];
    float* out = (float*)d_out;
    float* partial = (float*)d_ws;

    // N = 4194304 circles; 1024 blocks x 4 batches x 1024 circles each.
    int block = 256;
    int grid = 1024;

    GIOULOSS_19524921327670_stage1<<<grid, block, 0, stream>>>(x4, y4, partial);
    GIOULOSS_19524921327670_stage2<<<1, block, 0, stream>>>(partial, out);
}

// Round 6
// 114.578 us; speedup vs baseline: 1.0194x; 1.0194x over previous
//
#include <hip/hip_runtime.h>
#include <math.h>

// Circle GIoU loss, summed over N pairs.
// x, y: (N,3) float32 row-major [cx, cy, r]. Output: scalar float32 sum.
//
// R6: R3 structure (2048 blocks, 8 elem/thread, all loads up-front, two-stage
// reduce) + transcendental diet: squared-distance compares, rsqrt for 1/d,
// shared sqrt(h2) between Heron term and hull term, positive-arg acos for
// alpha. 11 -> 9 quarter-rate trans ops/element, fewer clamps/selects.
// NOTE: total dur_us carries ~89 us of fixed harness reset cost
// (268 MB d_ws poison + input restores) — controllable part is stage1+2.

#define EPSF   1e-07f
#define ACLIPF (1.0f - 1e-06f)
#define PIF    3.14159265358979323846f

__device__ __forceinline__ float frcp(float x)   { return __builtin_amdgcn_rcpf(x); }
__device__ __forceinline__ float fsqrt(float x)  { return __builtin_amdgcn_sqrtf(x); }
__device__ __forceinline__ float frsqrt(float x) { return __builtin_amdgcn_rsqf(x); }

// A&S 4.4.45: acos(x) ~ sqrt(1-x)*poly(x) on [0,1]; abs err < 6.7e-5
__device__ __forceinline__ float fast_acos_pos(float x) {   // requires x >= 0
    float p = fmaf(fmaf(fmaf(-0.0187293f, x, 0.0742610f), x, -0.2121144f), x, 1.5707288f);
    return fsqrt(1.0f - x) * p;
}
__device__ __forceinline__ float fast_acos(float x) {
    float ax = fabsf(x);
    float r = fast_acos_pos(ax);
    return x < 0.0f ? PIF - r : r;
}

__device__ __forceinline__ float circle_giou(float cx0, float cy0, float r0,
                                             float cx1, float cy1, float r1) {
    float dx = cx0 - cx1, dy = cy0 - cy1;
    float d2 = fmaxf(fmaf(dx, dx, dy * dy), EPSF);       // matches ref's max(d2,EPS) under sqrt
    float rmax = fmaxf(r0, r1), rmin = fminf(r0, r1);
    float rdiff = rmax - rmin, rsum = r0 + r1;
    float rdiff2 = rdiff * rdiff, rsum2 = rsum * rsum;

    // squared-distance comparisons (all quantities >= 0)
    bool lens      = (d2 < rsum2) && (d2 > rdiff2);
    bool contained = (d2 <= rdiff2);

    float invd = frsqrt(d2);          // 1/d
    float d    = d2 * invd;           // sqrt(d2)

    float r0s = r0 * r0, r1s = r1 * r1;
    // denominators 2*d*r > 0 always (d >= 3.16e-4, r > 0 a.s.); clamp after is enough
    float inv0 = frcp(2.0f * d * r0);
    float inv1 = frcp(2.0f * d * r1);
    float cos0 = fminf(fmaxf((d2 + r0s - r1s) * inv0, -ACLIPF), ACLIPF);
    float cos1 = fminf(fmaxf((d2 + r1s - r0s) * inv1, -ACLIPF), ACLIPF);

    // t = (rsum2-d2)*(d2-rdiff2); share sqrt(h2) with hull term
    float h2  = d2 - rdiff2;
    float sh2 = fsqrt(fmaxf(h2, EPSF));                  // sqrt(h2), valid when !contained
    float st  = fsqrt(fmaxf(rsum2 - d2, EPSF)) * sh2;    // = sqrt(t) when lens

    float lens_area = r0s * fast_acos(cos0) + r1s * fast_acos(cos1) - 0.5f * st;
    float inter = lens ? lens_area : (contained ? PIF * rmin * rmin : 0.0f);
    float uni = PIF * (r0s + r1s) - inter;
    float iou = inter * frcp(fmaxf(uni, EPSF));

    float alpha = fast_acos_pos(fminf(rdiff * invd, ACLIPF));   // arg in [0, ACLIP]
    float hull_open = rmax * rmax * (PIF - alpha) + rmin * rmin * alpha
                      + (rmax + rmin) * sh2;
    float hull = contained ? PIF * rmax * rmax : hull_open;

    return 1.0f - (iou - (hull - uni) * frcp(fmaxf(hull, EPSF)));
}

__device__ __forceinline__ float giou4(float4 xa, float4 xb, float4 xc,
                                       float4 ya, float4 yb, float4 yc) {
    float s = 0.0f;
    s += circle_giou(xa.x, xa.y, xa.z,  ya.x, ya.y, ya.z);
    s += circle_giou(xa.w, xb.x, xb.y,  ya.w, yb.x, yb.y);
    s += circle_giou(xb.z, xb.w, xc.x,  yb.z, yb.w, yc.x);
    s += circle_giou(xc.y, xc.z, xc.w,  yc.y, yc.z, yc.w);
    return s;
}

__global__ __launch_bounds__(256)
void GIOULOSS_19524921327670_stage1(const float4* __restrict__ x4,
                                    const float4* __restrict__ y4,
                                    float* __restrict__ partial, int nthreads) {
    int t = blockIdx.x * blockDim.x + threadIdx.x;
    int g0 = t, g1 = t + nthreads;   // two coalesced halves

    // Issue ALL 12 loads first; batch-1 loads in flight during batch-0 compute.
    float4 xa0 = x4[3 * g0 + 0], xb0 = x4[3 * g0 + 1], xc0 = x4[3 * g0 + 2];
    float4 ya0 = y4[3 * g0 + 0], yb0 = y4[3 * g0 + 1], yc0 = y4[3 * g0 + 2];
    float4 xa1 = x4[3 * g1 + 0], xb1 = x4[3 * g1 + 1], xc1 = x4[3 * g1 + 2];
    float4 ya1 = y4[3 * g1 + 0], yb1 = y4[3 * g1 + 1], yc1 = y4[3 * g1 + 2];

    float acc = giou4(xa0, xb0, xc0, ya0, yb0, yc0)
              + giou4(xa1, xb1, xc1, ya1, yb1, yc1);

    #pragma unroll
    for (int off = 32; off > 0; off >>= 1)
        acc += __shfl_down(acc, off, 64);

    __shared__ float wave_sums[4];
    int lane = threadIdx.x & 63;
    int wave = threadIdx.x >> 6;
    if (lane == 0) wave_sums[wave] = acc;
    __syncthreads();
    if (threadIdx.x == 0)
        partial[blockIdx.x] = wave_sums[0] + wave_sums[1] + wave_sums[2] + wave_sums[3];
}

// Sums 2048 block partials with one 256-thread block.
__global__ __launch_bounds__(256)
void GIOULOSS_19524921327670_stage2(const float* __restrict__ partial,
                                    float* __restrict__ out) {
    const float4* p4 = (const float4*)partial;   // 2048 floats = 512 float4
    float4 a = p4[threadIdx.x];
    float4 b = p4[threadIdx.x + 256];
    float acc = (a.x + a.y) + (a.z + a.w) + (b.x + b.y) + (b.z + b.w);

    #pragma unroll
    for (int off = 32; off > 0; off >>= 1)
        acc += __shfl_down(acc, off, 64);

    __shared__ float wave_sums[4];
    int lane = threadIdx.x & 63;
    int wave = threadIdx.x >> 6;
    if (lane == 0) wave_sums[wave] = acc;
    __syncthreads();
    if (threadIdx.x == 0)
        out[0] = wave_sums[0] + wave_sums[1] + wave_sums[2] + wave_sums[3];
}

extern "C" void kernel_launch(void* const* d_in, const int* in_sizes, int n_in,
                              void* d_out, int out_size, void* d_ws, size_t ws_size,
                              hipStream_t stream) {
    const float4* x4 = (const float4*)d_in[0];
    const float4* y4 = (const float4*)d_in[1];
    float* out = (float*)d_out;
    float* partial = (float*)d_ws;

    int n = in_sizes[0] / 3;      // 4194304 circle pairs
    int ngroups = n / 4;          // 1048576 groups of 4
    int nthreads = ngroups / 2;   // 524288 threads, 2 groups (8 elems) each
    int block = 256;
    int grid = nthreads / block;  // 2048 blocks -> 2048 partials

    GIOULOSS_19524921327670_stage1<<<grid, block, 0, stream>>>(x4, y4, partial, nthreads);
    GIOULOSS_19524921327670_stage2<<<1, block, 0, stream>>>(partial, out);
}